// Round 14
// baseline (202.912 us; speedup 1.0000x reference)
//
#include <hip/hip_runtime.h>
#include <hip/hip_bf16.h>
#include <math.h>

#define K_CB 2
#define DIM 128
#define NEMB 4096
#define HW 1024
#define NPK 32768
#define CCH 256
#define MARGIN_ACC 0.065f   // margin in acc units (= score/2); score-margin 0.13

typedef __attribute__((ext_vector_type(8))) _Float16 half8;
typedef __attribute__((ext_vector_type(4))) float f32x4;
typedef unsigned long long u64;

// ---------------- embed -> fp16 [k][j][d] transpose + ||e||^2 (+512, halved) + scratch zero ----------------
__global__ void k_prep(const float* __restrict__ embed, ushort* __restrict__ ebf,
                       float* __restrict__ enorm, float* __restrict__ en512,
                       int* __restrict__ hist, int* __restrict__ cnt, u64* __restrict__ slots) {
    __shared__ ushort tile[DIM][130];
    __shared__ float psum[2][128];
    const int t = threadIdx.x;
    const int gb = blockIdx.x * 256 + t;          // 0..16383
#pragma unroll
    for (int i = 0; i < 4; ++i) slots[gb * 4 + i] = ~0ull;   // 65536 slots
    if (gb < K_CB * NEMB) hist[gb] = 0;
    if (gb < K_CB) cnt[gb] = 0;

    const int k = blockIdx.x >> 5;
    const int j0 = (blockIdx.x & 31) * 128;
    const int jj = t & 127, half = t >> 7;
    const float* ek = embed + (size_t)k * DIM * NEMB;
    float s = 0.f;
    for (int i = 0; i < 64; ++i) {
        int d = i * 2 + half;
        float v = ek[(size_t)d * NEMB + j0 + jj];
        s = fmaf(v, v, s);
        _Float16 h = (_Float16)v;
        tile[d][jj] = *(ushort*)&h;
    }
    psum[half][jj] = s;
    __syncthreads();
    if (t < 128) {
        float e = psum[0][t] + psum[1][t];
        enorm[k * NEMB + j0 + t] = e;                   // exact, for rescore
        en512[k * NEMB + j0 + t] = (e + 512.f) * 0.5f;  // MFMA C-init: acc = (score+512)/2
    }
    ushort* outk = ebf + ((size_t)k * NEMB + j0) * DIM;
    for (int i = 0; i < 64; ++i) {
        int idx = i * 256 + t;
        int jx = idx >> 7, d = idx & 127;
        outk[(size_t)jx * DIM + d] = tile[d][jx];
    }
}

// ---------------- coarse fp16 MFMA scoring, en-in-accumulator + packed (acc|jloc) epilogue ----------------
// block (k, 128 rows), 512 threads = 8 waves (wm row-quarter x wjj j-half), wave tile 32r x 64j.
// A in registers (negated once) so MFMA computes C - x.e, C = (||e||^2+512)/2.
// launch_bounds(512,2): 2 blocks/CU (the LDS limit anyway) -> 128-VGPR budget, which lets us
// precompute the 16 ds-read addrs + 4 staging src offsets without the round-10 spill.
#define STAGE_B2(stgoff, jt_) do { \
    const char* gbase_ = ebk_c + (size_t)(jt_) * 32768; \
    _Pragma("unroll") \
    for (int it = 0; it < 4; ++it) { \
        __builtin_amdgcn_global_load_lds( \
            (const __attribute__((address_space(1))) unsigned int*)(gbase_ + sof[it]), \
            (__attribute__((address_space(3))) unsigned int*)(smem + (stgoff) + ldsb + it * 8192), \
            16, 0, 0); \
    } \
} while (0)

#define SCORE_STEP(jt_, BCOFF, STGOFF) do { \
    if ((jt_) < 31) STAGE_B2(STGOFF, (jt_) + 1); \
    float en_[4]; \
    _Pragma("unroll") \
    for (int jf = 0; jf < 4; ++jf) en_[jf] = enk[(jt_) * 128 + wjj * 64 + jf * 16 + l15]; \
    f32x4 acc[2][4]; \
    _Pragma("unroll") \
    for (int kk = 0; kk < 4; ++kk) { \
        half8 bb[4]; \
        _Pragma("unroll") \
        for (int jf = 0; jf < 4; ++jf) \
            bb[jf] = *(const half8*)(smem + (BCOFF) + ads[kk * 4 + jf]); \
        _Pragma("unroll") \
        for (int mf = 0; mf < 2; ++mf) \
            _Pragma("unroll") \
            for (int jf = 0; jf < 4; ++jf) \
                acc[mf][jf] = __builtin_amdgcn_mfma_f32_16x16x32_f16( \
                    areg[mf][kk], bb[jf], \
                    (kk == 0) ? (f32x4){en_[jf], en_[jf], en_[jf], en_[jf]} : acc[mf][jf], \
                    0, 0, 0); \
    } \
    _Pragma("unroll") \
    for (int mf = 0; mf < 2; ++mf) \
        _Pragma("unroll") \
        for (int r = 0; r < 4; ++r) { \
            int ti = mf * 4 + r; \
            float p0 = __uint_as_float((__float_as_uint(acc[mf][0][r]) & 0xFFFFFF80u) | (jlbase)); \
            float p1 = __uint_as_float((__float_as_uint(acc[mf][1][r]) & 0xFFFFFF80u) | (jlbase + 16)); \
            float p2 = __uint_as_float((__float_as_uint(acc[mf][2][r]) & 0xFFFFFF80u) | (jlbase + 32)); \
            float p3 = __uint_as_float((__float_as_uint(acc[mf][3][r]) & 0xFFFFFF80u) | (jlbase + 48)); \
            float m = fminf(fminf(p0, p1), fminf(p2, p3)); \
            second[ti] = fminf(second[ti], fmaxf(m, best[ti])); \
            bool lt = m < best[ti]; \
            bchunk[ti] = lt ? (jt_) : bchunk[ti]; \
            best[ti] = fminf(best[ti], m); \
        } \
    __syncthreads(); \
} while (0)

__launch_bounds__(512, 2)
__global__ void k_score(const float* __restrict__ x, const ushort* __restrict__ ebf,
                        const float* __restrict__ en512, int* __restrict__ idxw,
                        float* __restrict__ bestv, float* __restrict__ rnorm,
                        int* __restrict__ list, int* __restrict__ cnt)
{
    __shared__ __align__(16) char smem[65536];
    __shared__ float rn[4][128];

    const int blk = blockIdx.x;
    const int k = blk >> 8;
    const int n0 = (blk & 255) * 128;
    const int b = n0 >> 10;
    const int hw0 = n0 & (HW - 1);
    const int t = threadIdx.x;          // 0..511
    const int lane = t & 63;
    const int w = t >> 6;               // 0..7
    const int wm = w >> 1;              // row quarter
    const int wjj = w & 1;              // j half
    const int l15 = lane & 15, l4 = lane >> 4;

    const ushort* ebk = ebf + (size_t)k * NEMB * DIM;
    const char* ebk_c = (const char*)ebk;
    const float* enk = en512 + k * NEMB;
    const float* xk = x + ((size_t)(b * CCH + k * DIM)) * HW + hw0;

    // ---- prologue: stage A [n=128][d=128] fp16 swizzled (uses both B buffers' space) ----
    {
        const int h = t & 127, q = t >> 7;   // q 0..3 (d-quarter)
        float s = 0.f;
        for (int i = 0; i < 16; ++i) {
            int d2 = q * 32 + i * 2;
            float v0 = xk[(size_t)d2 * HW + h];
            float v1 = xk[(size_t)(d2 + 1) * HW + h];
            s = fmaf(v0, v0, fmaf(v1, v1, s));
            _Float16 h0 = (_Float16)v0, h1 = (_Float16)v1;
            unsigned int u = ((unsigned int)*(ushort*)&h0) | (((unsigned int)*(ushort*)&h1) << 16);
            int byte = h * 256 + ((d2 * 2) ^ ((h & 15) << 4));
            *(unsigned int*)(smem + byte) = u;
        }
        rn[q][h] = s;
    }
    __syncthreads();
    if (t < 128) rnorm[k * NPK + n0 + t] = rn[0][t] + rn[1][t] + rn[2][t] + rn[3][t];

    // ---- A-frags to registers (2 mf x 4 kk), then negate fp16 signs once ----
    half8 areg[2][4];
#pragma unroll
    for (int mf = 0; mf < 2; ++mf)
#pragma unroll
        for (int kk = 0; kk < 4; ++kk) {
            int row = wm * 32 + mf * 16 + l15;
            int byte = row * 256 + ((kk * 64 + l4 * 16) ^ ((row & 15) << 4));
            areg[mf][kk] = *(const half8*)(smem + byte);
            unsigned int* p = (unsigned int*)&areg[mf][kk];
#pragma unroll
            for (int q2 = 0; q2 < 4; ++q2) p[q2] ^= 0x80008000u;
        }
    __syncthreads();   // A reads done before B staging overwrites

    // ---- precomputed addressing (VGPR budget 128 under (512,2): no spill) ----
    int sof[4];                         // staging src offsets within a 32KB B tile
#pragma unroll
    for (int it = 0; it < 4; ++it) {
        int seg = it * 512 + t;
        int row = seg >> 4, slot = seg & 15;
        sof[it] = row * 256 + ((slot * 16) ^ ((row & 15) << 4));
    }
    const int ldsb = (t & ~63) * 16;    // wave-uniform LDS dest base (+ it*8192)
    int ads[16];                        // ds_read_b128 byte addrs (Bs0 base; +32768 imm for Bs1)
#pragma unroll
    for (int kk = 0; kk < 4; ++kk)
#pragma unroll
        for (int jf = 0; jf < 4; ++jf) {
            int row = wjj * 64 + jf * 16 + l15;
            ads[kk * 4 + jf] = row * 256 + ((kk * 64 + l4 * 16) ^ ((row & 15) << 4));
        }

    STAGE_B2(0, 0);
    __syncthreads();   // Bs0 ready

    const int jlbase = wjj * 64 + l15;   // low-7 jloc base for this lane

    float best[8], second[8];
    int bchunk[8];
#pragma unroll
    for (int i = 0; i < 8; ++i) { best[i] = 3.4e38f; second[i] = 3.4e38f; bchunk[i] = 0; }

    for (int jt2 = 0; jt2 < 16; ++jt2) {
        SCORE_STEP(jt2 * 2,     0,     32768);   // compute Bs0, stage into Bs1
        SCORE_STEP(jt2 * 2 + 1, 32768, 0);       // compute Bs1, stage into Bs0
    }

    // ---- merge across the 16 j-lanes sharing each row (packed values distinct per lane) ----
#pragma unroll
    for (int off = 1; off < 16; off <<= 1) {
#pragma unroll
        for (int ti = 0; ti < 8; ++ti) {
            float ob = __shfl_xor(best[ti], off);
            float os = __shfl_xor(second[ti], off);
            int oc = __shfl_xor(bchunk[ti], off);
            float ns = fminf(fmaxf(best[ti], ob), fminf(second[ti], os));
            bool take = ob < best[ti];
            bchunk[ti] = take ? oc : bchunk[ti];
            best[ti] = fminf(best[ti], ob);
            second[ti] = ns;
        }
    }

    // ---- merge the two wjj waves per row via LDS ----
    __syncthreads();
    float* tb = (float*)smem;          // [128][2]
    float* ts = tb + 256;              // [128][2]
    int*   tc = (int*)(ts + 256);      // [128][2]
    if (l15 == 0) {
#pragma unroll
        for (int ti = 0; ti < 8; ++ti) {
            int mf = ti >> 2, r = ti & 3;
            int row = wm * 32 + mf * 16 + l4 * 4 + r;
            tb[row * 2 + wjj] = best[ti];
            ts[row * 2 + wjj] = second[ti];
            tc[row * 2 + wjj] = bchunk[ti];
        }
    }
    __syncthreads();
    if (t < 128) {
        float b0 = tb[t * 2], b1 = tb[t * 2 + 1];
        float s0 = ts[t * 2], s1 = ts[t * 2 + 1];
        int   c0 = tc[t * 2], c1 = tc[t * 2 + 1];
        bool take1 = b1 < b0;                    // packed values distinct (wjj bit)
        float nb = fminf(b0, b1);
        float ns = fminf(fmaxf(b0, b1), fminf(s0, s1));
        int   nc = take1 ? c1 : c0;
        unsigned int nbits = __float_as_uint(nb);
        int nj = nc * 128 + (int)(nbits & 127u);
        int gidx = k * NPK + n0 + t;
        idxw[gidx] = nj;
        float up = __uint_as_float(nbits & 0xFFFFFF80u);   // acc units
        bestv[gidx] = fmaf(2.f, up, -512.f);               // back to score units
        if (ns - nb < MARGIN_ACC) {
            int p = atomicAdd(&cnt[k], 1);
            list[k * NPK + p] = gidx;
        }
    }
}

// ---------------- exact fp32 rescore: (4-row chunk) x (256-j slab) items [round-9 proven] ----------------
__global__ void k_rescore(const float* __restrict__ x, const float* __restrict__ embed,
                          const float* __restrict__ enorm, const int* __restrict__ list,
                          const int* __restrict__ cnt, u64* __restrict__ slots)
{
    __shared__ float xr[4][128];
    __shared__ u64 part[4][4];
    const int t = threadIdx.x;
    const int lane = t & 63, wv = t >> 6;
    const int c0 = cnt[0], c1 = cnt[1];
    const int items0 = ((c0 + 3) >> 2) * 16;
    const int items1 = ((c1 + 3) >> 2) * 16;
    const int total = items0 + items1;

    for (int item = blockIdx.x; item < total; item += gridDim.x) {
        int k, c, sl, ck;
        if (item < items0) { k = 0; c = item >> 4; sl = item & 15; ck = c0; }
        else { int it2 = item - items0; k = 1; c = it2 >> 4; sl = it2 & 15; ck = c1; }
        const int base = c * 4;
        const int cn = min(4, ck - base);
        __syncthreads();   // xr/part reuse safety
        for (int ii = t; ii < cn * 128; ii += 256) {
            int ri = ii >> 7, d = ii & 127;
            int gidx = list[k * NPK + base + ri];
            int n = gidx & (NPK - 1);
            int bb = n >> 10, hw = n & 1023;
            xr[ri][d] = x[((size_t)(bb * CCH + k * DIM + d)) * HW + hw];
        }
        __syncthreads();

        const int j = sl * 256 + t;
        float dot[4];
#pragma unroll
        for (int ri = 0; ri < 4; ++ri) dot[ri] = 0.f;
        const float* ek = embed + (size_t)k * DIM * NEMB + j;
        for (int d = 0; d < DIM; ++d) {
            float ev = ek[(size_t)d * NEMB];
#pragma unroll
            for (int ri = 0; ri < 4; ++ri) dot[ri] = fmaf(xr[ri][d], ev, dot[ri]);
        }
        const float en = enorm[k * NEMB + j];
        u64 key[4];
#pragma unroll
        for (int ri = 0; ri < 4; ++ri) {
            float sc = fmaf(-2.f, dot[ri], en);
            unsigned int bits = __float_as_uint(sc);
            unsigned int u = (sc >= 0.f) ? (bits | 0x80000000u) : ~bits;
            key[ri] = ((u64)u << 32) | (unsigned int)j;
        }
#pragma unroll
        for (int off = 32; off; off >>= 1) {
#pragma unroll
            for (int ri = 0; ri < 4; ++ri) {
                u64 o = __shfl_xor(key[ri], off);
                key[ri] = o < key[ri] ? o : key[ri];
            }
        }
        if (lane == 0) {
#pragma unroll
            for (int ri = 0; ri < 4; ++ri) part[wv][ri] = key[ri];
        }
        __syncthreads();
        if (t < 16) {
            int ri = t >> 2, w2 = t & 3;
            u64 kk2 = part[w2][ri];
            u64 o = __shfl_xor(kk2, 1); kk2 = o < kk2 ? o : kk2;
            o = __shfl_xor(kk2, 2);     kk2 = o < kk2 ? o : kk2;
            if (w2 == 0 && ri < cn)
                atomicMin(&slots[k * NPK + base + ri], kk2);
        }
    }
}

// ---------------- write rescored winners + exact scores back ----------------
__global__ void k_fixup(const int* __restrict__ list, const int* __restrict__ cnt,
                        const u64* __restrict__ slots, int* __restrict__ idxw,
                        float* __restrict__ bestv) {
    int g = blockIdx.x * 256 + threadIdx.x;
#pragma unroll
    for (int k = 0; k < K_CB; ++k)
        if (g < cnt[k]) {
            u64 sl = slots[k * NPK + g];
            int gidx = list[k * NPK + g];
            idxw[gidx] = (int)(sl & 0xFFFFFFFFu);
            unsigned int u = (unsigned int)(sl >> 32);
            unsigned int bits = (u & 0x80000000u) ? (u & 0x7FFFFFFFu) : ~u;
            bestv[gidx] = __uint_as_float(bits);
        }
}

// ---------------- gather z_q + argf/hist (emit fused) ----------------
__global__ void k_gather(const float* __restrict__ embed, const int* __restrict__ idx,
                         float* __restrict__ zq, float* __restrict__ argf,
                         int* __restrict__ hist)
{
    const int blk = blockIdx.x;           // k*4096 + b*128 + d
    const int k = blk >> 12;
    const int b = (blk >> 7) & 31;
    const int d = blk & 127;
    const float* erow = embed + ((size_t)k * DIM + d) * NEMB;
    const int* idxr = idx + k * NPK + b * HW;
    float* zr = zq + ((size_t)b * CCH + (size_t)k * DIM + d) * HW;
    const int t = threadIdx.x;
#pragma unroll
    for (int i = 0; i < 4; ++i) {
        int h = i * 256 + t;
        int j = idxr[h];
        zr[h] = erow[j];
        if (d == 0) {
            argf[k * NPK + b * HW + h] = (float)j;
            atomicAdd(&hist[k * NEMB + j], 1);
        }
    }
}

// ---------------- diff partial sums: 64 blocks over the flat 65536 rows ----------------
__global__ void k_dsum(const float* __restrict__ rnorm, const float* __restrict__ bestv,
                       float* __restrict__ dpart)
{
    __shared__ float red[256];
    const int t = threadIdx.x;
    const int base = blockIdx.x * 1024;
    float s = 0.f;
#pragma unroll
    for (int i = 0; i < 4; ++i) {
        int g = base + i * 256 + t;
        s += rnorm[g] + bestv[g];
    }
    red[t] = s;
    __syncthreads();
    for (int off = 128; off > 0; off >>= 1) {
        if (t < off) red[t] += red[t + off];
        __syncthreads();
    }
    if (t == 0) dpart[blockIdx.x] = red[0];
}

// ---------------- finalize diffs + perplexity ----------------
__global__ void k_ppl(const float* __restrict__ dpart, const int* __restrict__ hist,
                      float* __restrict__ diffs, float* __restrict__ ppls)
{
    const int k = blockIdx.x;
    const int t = threadIdx.x;
    __shared__ float red[256];
    red[t] = (t < 32) ? dpart[k * 32 + t] : 0.f;
    __syncthreads();
    for (int off = 128; off > 0; off >>= 1) {
        if (t < off) red[t] += red[t + off];
        __syncthreads();
    }
    if (t == 0) diffs[k] = red[0] / (float)((size_t)NPK * DIM);
    __syncthreads();
    float s2 = 0.f;
    for (int i = t; i < NEMB; i += 256) {
        float p = (float)hist[k * NEMB + i] * (1.0f / (float)NPK);
        s2 += p * logf(p + 1e-10f);
    }
    red[t] = s2;
    __syncthreads();
    for (int off = 128; off > 0; off >>= 1) {
        if (t < off) red[t] += red[t + off];
        __syncthreads();
    }
    if (t == 0) ppls[k] = expf(-red[0]);
}

extern "C" void kernel_launch(void* const* d_in, const int* in_sizes, int n_in,
                              void* d_out, int out_size, void* d_ws, size_t ws_size,
                              hipStream_t stream) {
    const float* x = (const float*)d_in[0];       // [32,256,32,32]
    const float* embed = (const float*)d_in[1];   // [2,128,4096]
    float* out = (float*)d_out;
    float* zq    = out;                 // 8388608
    float* diffs = out + 8388608;       // 2
    float* argf  = out + 8388610;       // 65536 ([K,B,H,W] as float)
    float* ppls  = out + 8454146;       // 2

    char* W = (char*)d_ws;
    ushort* ebf   = (ushort*)W;                    // 2,097,152 : embedT fp16 [2][4096][128]
    float* enorm  = (float*)(W + 2097152);         // 32768 (exact, rescore)
    float* en512  = (float*)(W + 2129920);         // 32768 ((e+512)/2, coarse C-init)
    int*   idx    = (int*)(W + 2162688);           // 262144
    int*   hist   = (int*)(W + 2424832);           // 32768
    float* rnorm  = (float*)(W + 2457600);         // 262144
    float* bestv  = (float*)(W + 2719744);         // 262144
    int*   list   = (int*)(W + 2981888);           // 262144
    int*   cnt    = (int*)(W + 3244032);           // 64
    u64*   slots  = (u64*)(W + 3244096);           // 524288
    float* dpart  = (float*)(W + 3768384);         // 256 -> ends ~3.77 MB

    k_prep   <<<64,   256, 0, stream>>>(embed, ebf, enorm, en512, hist, cnt, slots);
    k_score  <<<512,  512, 0, stream>>>(x, ebf, en512, idx, bestv, rnorm, list, cnt);
    k_rescore<<<4096, 256, 0, stream>>>(x, embed, enorm, list, cnt, slots);
    k_fixup  <<<128,  256, 0, stream>>>(list, cnt, slots, idx, bestv);
    k_gather <<<8192, 256, 0, stream>>>(embed, idx, zq, argf, hist);
    k_dsum   <<<64,   256, 0, stream>>>(rnorm, bestv, dpart);
    k_ppl    <<<2,    256, 0, stream>>>(dpart, hist, diffs, ppls);
}

// Round 15
// 195.562 us; speedup vs baseline: 1.0376x; 1.0376x over previous
//
#include <hip/hip_runtime.h>
#include <hip/hip_bf16.h>
#include <math.h>

#define K_CB 2
#define DIM 128
#define NEMB 4096
#define HW 1024
#define NPK 32768
#define CCH 256
#define MARGIN 0.13f

typedef __attribute__((ext_vector_type(8))) _Float16 half8;
typedef __attribute__((ext_vector_type(4))) float f32x4;
typedef unsigned long long u64;

// ---------------- embed -> fp16 [k][j][d] transpose + ||e||^2 (+512 copy) + scratch zero ----------------
__global__ void k_prep(const float* __restrict__ embed, ushort* __restrict__ ebf,
                       float* __restrict__ enorm, float* __restrict__ en512,
                       int* __restrict__ hist, int* __restrict__ cnt, u64* __restrict__ slots) {
    __shared__ ushort tile[DIM][130];
    __shared__ float psum[2][128];
    const int t = threadIdx.x;
    const int gb = blockIdx.x * 256 + t;          // 0..16383
#pragma unroll
    for (int i = 0; i < 4; ++i) slots[gb * 4 + i] = ~0ull;   // 65536 slots
    if (gb < K_CB * NEMB) hist[gb] = 0;
    if (gb < K_CB) cnt[gb] = 0;

    const int k = blockIdx.x >> 5;
    const int j0 = (blockIdx.x & 31) * 128;
    const int jj = t & 127, half = t >> 7;
    const float* ek = embed + (size_t)k * DIM * NEMB;
    float s = 0.f;
    for (int i = 0; i < 64; ++i) {
        int d = i * 2 + half;
        float v = ek[(size_t)d * NEMB + j0 + jj];
        s = fmaf(v, v, s);
        _Float16 h = (_Float16)v;
        tile[d][jj] = *(ushort*)&h;
    }
    psum[half][jj] = s;
    __syncthreads();
    if (t < 128) {
        float e = psum[0][t] + psum[1][t];
        enorm[k * NEMB + j0 + t] = e;           // exact, for rescore
        en512[k * NEMB + j0 + t] = e + 512.f;   // shifted, for coarse packed scoring
    }
    ushort* outk = ebf + ((size_t)k * NEMB + j0) * DIM;
    for (int i = 0; i < 64; ++i) {
        int idx = i * 256 + t;
        int jx = idx >> 7, d = idx & 127;
        outk[(size_t)jx * DIM + d] = tile[d][jx];
    }
}

// ---------------- coarse fp16 MFMA scoring, packed (score|jloc) epilogue ----------------
// block (k, 128 rows), 512 threads = 8 waves as (wm 0..3 row-quarters) x (wjj 0..1 j-halves).
// Wave tile 32 rows x 64 j. A in registers; B 2x32KB double-buffered; 4-bit XOR swizzle.
// Scores shifted +512 (positive) -> low 7 mantissa bits carry jloc (perturb <= 0.008).
// REGISTER BUDGET (rounds 10/14 lesson): total arch+acc regs must stay <=128 for
// 2 blocks/CU (unified VGPR/AGPR file; 4 waves/SIMD x 128 = 512 pool). Do NOT add
// live arrays (address precompute etc.) — occupancy halves and time regresses.
#define STAGE_B(dst, jt_) do { \
    _Pragma("unroll") \
    for (int it = 0; it < 4; ++it) { \
        int seg_ = it * 512 + t; \
        int row_ = seg_ >> 4; \
        int slot_ = seg_ & 15; \
        int src_ = row_ * 256 + ((slot_ * 16) ^ ((row_ & 15) << 4)); \
        const char* g_ = (const char*)ebk + (size_t)(jt_) * 32768 + src_; \
        char* l_ = (char*)(dst) + (it * 512 + (t & ~63)) * 16; \
        __builtin_amdgcn_global_load_lds( \
            (const __attribute__((address_space(1))) unsigned int*)g_, \
            (__attribute__((address_space(3))) unsigned int*)l_, 16, 0, 0); \
    } \
} while (0)

__launch_bounds__(512, 4)
__global__ void k_score(const float* __restrict__ x, const ushort* __restrict__ ebf,
                        const float* __restrict__ en512, int* __restrict__ idxw,
                        float* __restrict__ bestv, float* __restrict__ rnorm,
                        int* __restrict__ list, int* __restrict__ cnt)
{
    __shared__ __align__(16) char smem[65536];
    __shared__ float rn[4][128];
    char* Bs0 = smem;
    char* Bs1 = smem + 32768;

    const int blk = blockIdx.x;
    const int k = blk >> 8;
    const int n0 = (blk & 255) * 128;
    const int b = n0 >> 10;
    const int hw0 = n0 & (HW - 1);
    const int t = threadIdx.x;          // 0..511
    const int lane = t & 63;
    const int w = t >> 6;               // 0..7
    const int wm = w >> 1;              // row quarter
    const int wjj = w & 1;              // j half
    const int l15 = lane & 15, l4 = lane >> 4;

    const ushort* ebk = ebf + (size_t)k * NEMB * DIM;
    const float* enk = en512 + k * NEMB;
    const float* xk = x + ((size_t)(b * CCH + k * DIM)) * HW + hw0;

    // ---- prologue: stage A [n=128][d=128] fp16 swizzled (uses both B buffers' space) ----
    {
        const int h = t & 127, q = t >> 7;   // q 0..3 (d-quarter)
        float s = 0.f;
        for (int i = 0; i < 16; ++i) {
            int d2 = q * 32 + i * 2;
            float v0 = xk[(size_t)d2 * HW + h];
            float v1 = xk[(size_t)(d2 + 1) * HW + h];
            s = fmaf(v0, v0, fmaf(v1, v1, s));
            _Float16 h0 = (_Float16)v0, h1 = (_Float16)v1;
            unsigned int u = ((unsigned int)*(ushort*)&h0) | (((unsigned int)*(ushort*)&h1) << 16);
            int byte = h * 256 + ((d2 * 2) ^ ((h & 15) << 4));
            *(unsigned int*)(smem + byte) = u;
        }
        rn[q][h] = s;
    }
    __syncthreads();
    if (t < 128) rnorm[k * NPK + n0 + t] = rn[0][t] + rn[1][t] + rn[2][t] + rn[3][t];

    // ---- A-frags to registers: 2 mf x 4 kk (this wave's 32 rows) ----
    half8 areg[2][4];
#pragma unroll
    for (int mf = 0; mf < 2; ++mf)
#pragma unroll
        for (int kk = 0; kk < 4; ++kk) {
            int row = wm * 32 + mf * 16 + l15;
            int byte = row * 256 + ((kk * 64 + l4 * 16) ^ ((row & 15) << 4));
            areg[mf][kk] = *(const half8*)(smem + byte);
        }
    __syncthreads();   // A reads done before B staging overwrites

    STAGE_B(Bs0, 0);
    __syncthreads();   // Bs0 ready

    const f32x4 z4 = {0.f, 0.f, 0.f, 0.f};
    const int jlbase = wjj * 64 + l15;   // low-7 jloc base for this lane

    float best[8], second[8];
    int bchunk[8];
#pragma unroll
    for (int i = 0; i < 8; ++i) { best[i] = 3.4e38f; second[i] = 3.4e38f; bchunk[i] = 0; }

    for (int jt = 0; jt < 32; ++jt) {
        const char* Bc = (jt & 1) ? Bs1 : Bs0;
        char* Bn = (jt & 1) ? Bs0 : Bs1;
        if (jt < 31) STAGE_B(Bn, jt + 1);

        f32x4 acc[2][4];
#pragma unroll
        for (int kk = 0; kk < 4; ++kk) {
            half8 bb[4];
#pragma unroll
            for (int jf = 0; jf < 4; ++jf) {
                int row = wjj * 64 + jf * 16 + l15;
                int byte = row * 256 + ((kk * 64 + l4 * 16) ^ ((row & 15) << 4));
                bb[jf] = *(const half8*)(Bc + byte);
            }
#pragma unroll
            for (int mf = 0; mf < 2; ++mf)
#pragma unroll
                for (int jf = 0; jf < 4; ++jf)
                    acc[mf][jf] = __builtin_amdgcn_mfma_f32_16x16x32_f16(
                        areg[mf][kk], bb[jf], (kk == 0) ? z4 : acc[mf][jf], 0, 0, 0);
        }

        // ---- epilogue: packed (score|jloc), per-row min-tree + (best, second, chunk) ----
        float en[4];
#pragma unroll
        for (int jf = 0; jf < 4; ++jf) en[jf] = enk[jt * 128 + wjj * 64 + jf * 16 + l15];
#pragma unroll
        for (int mf = 0; mf < 2; ++mf)
#pragma unroll
            for (int r = 0; r < 4; ++r) {
                int ti = mf * 4 + r;
                float p0 = __uint_as_float((__float_as_uint(fmaf(-2.f, acc[mf][0][r], en[0])) & 0xFFFFFF80u) | (jlbase));
                float p1 = __uint_as_float((__float_as_uint(fmaf(-2.f, acc[mf][1][r], en[1])) & 0xFFFFFF80u) | (jlbase + 16));
                float p2 = __uint_as_float((__float_as_uint(fmaf(-2.f, acc[mf][2][r], en[2])) & 0xFFFFFF80u) | (jlbase + 32));
                float p3 = __uint_as_float((__float_as_uint(fmaf(-2.f, acc[mf][3][r], en[3])) & 0xFFFFFF80u) | (jlbase + 48));
                float m = fminf(fminf(p0, p1), fminf(p2, p3));
                second[ti] = fminf(second[ti], fmaxf(m, best[ti]));
                bool lt = m < best[ti];
                bchunk[ti] = lt ? jt : bchunk[ti];
                best[ti] = fminf(best[ti], m);
            }
        __syncthreads();   // next tile's staged buffer ready
    }

    // ---- merge across the 16 j-lanes sharing each row (packed values distinct per lane) ----
#pragma unroll
    for (int off = 1; off < 16; off <<= 1) {
#pragma unroll
        for (int ti = 0; ti < 8; ++ti) {
            float ob = __shfl_xor(best[ti], off);
            float os = __shfl_xor(second[ti], off);
            int oc = __shfl_xor(bchunk[ti], off);
            float ns = fminf(fmaxf(best[ti], ob), fminf(second[ti], os));
            bool take = ob < best[ti];
            bchunk[ti] = take ? oc : bchunk[ti];
            best[ti] = fminf(best[ti], ob);
            second[ti] = ns;
        }
    }

    // ---- merge the two wjj waves per row via LDS ----
    __syncthreads();
    float* tb = (float*)smem;          // [128][2]
    float* ts = tb + 256;              // [128][2]
    int*   tc = (int*)(ts + 256);      // [128][2]
    if (l15 == 0) {
#pragma unroll
        for (int ti = 0; ti < 8; ++ti) {
            int mf = ti >> 2, r = ti & 3;
            int row = wm * 32 + mf * 16 + l4 * 4 + r;
            tb[row * 2 + wjj] = best[ti];
            ts[row * 2 + wjj] = second[ti];
            tc[row * 2 + wjj] = bchunk[ti];
        }
    }
    __syncthreads();
    if (t < 128) {
        float b0 = tb[t * 2], b1 = tb[t * 2 + 1];
        float s0 = ts[t * 2], s1 = ts[t * 2 + 1];
        int   c0 = tc[t * 2], c1 = tc[t * 2 + 1];
        bool take1 = b1 < b0;                    // packed values distinct (wjj bit)
        float nb = fminf(b0, b1);
        float ns = fminf(fmaxf(b0, b1), fminf(s0, s1));
        int   nc = take1 ? c1 : c0;
        unsigned int nbits = __float_as_uint(nb);
        int nj = nc * 128 + (int)(nbits & 127u);
        int gidx = k * NPK + n0 + t;
        idxw[gidx] = nj;
        bestv[gidx] = __uint_as_float(nbits & 0xFFFFFF80u) - 512.f;
        if (ns - nb < MARGIN) {
            int p = atomicAdd(&cnt[k], 1);
            list[k * NPK + p] = gidx;
        }
    }
}

// ---------------- exact fp32 rescore: (4-row chunk) x (256-j slab) items ----------------
__global__ void k_rescore(const float* __restrict__ x, const float* __restrict__ embed,
                          const float* __restrict__ enorm, const int* __restrict__ list,
                          const int* __restrict__ cnt, u64* __restrict__ slots)
{
    __shared__ float xr[4][128];
    __shared__ u64 part[4][4];
    const int t = threadIdx.x;
    const int lane = t & 63, wv = t >> 6;
    const int c0 = cnt[0], c1 = cnt[1];
    const int items0 = ((c0 + 3) >> 2) * 16;
    const int items1 = ((c1 + 3) >> 2) * 16;
    const int total = items0 + items1;

    for (int item = blockIdx.x; item < total; item += gridDim.x) {
        int k, c, sl, ck;
        if (item < items0) { k = 0; c = item >> 4; sl = item & 15; ck = c0; }
        else { int it2 = item - items0; k = 1; c = it2 >> 4; sl = it2 & 15; ck = c1; }
        const int base = c * 4;
        const int cn = min(4, ck - base);
        __syncthreads();   // xr/part reuse safety
        for (int ii = t; ii < cn * 128; ii += 256) {
            int ri = ii >> 7, d = ii & 127;
            int gidx = list[k * NPK + base + ri];
            int n = gidx & (NPK - 1);
            int bb = n >> 10, hw = n & 1023;
            xr[ri][d] = x[((size_t)(bb * CCH + k * DIM + d)) * HW + hw];
        }
        __syncthreads();

        const int j = sl * 256 + t;
        float dot[4];
#pragma unroll
        for (int ri = 0; ri < 4; ++ri) dot[ri] = 0.f;
        const float* ek = embed + (size_t)k * DIM * NEMB + j;
        for (int d = 0; d < DIM; ++d) {
            float ev = ek[(size_t)d * NEMB];
#pragma unroll
            for (int ri = 0; ri < 4; ++ri) dot[ri] = fmaf(xr[ri][d], ev, dot[ri]);
        }
        const float en = enorm[k * NEMB + j];
        u64 key[4];
#pragma unroll
        for (int ri = 0; ri < 4; ++ri) {
            float sc = fmaf(-2.f, dot[ri], en);
            unsigned int bits = __float_as_uint(sc);
            unsigned int u = (sc >= 0.f) ? (bits | 0x80000000u) : ~bits;
            key[ri] = ((u64)u << 32) | (unsigned int)j;
        }
#pragma unroll
        for (int off = 32; off; off >>= 1) {
#pragma unroll
            for (int ri = 0; ri < 4; ++ri) {
                u64 o = __shfl_xor(key[ri], off);
                key[ri] = o < key[ri] ? o : key[ri];
            }
        }
        if (lane == 0) {
#pragma unroll
            for (int ri = 0; ri < 4; ++ri) part[wv][ri] = key[ri];
        }
        __syncthreads();
        if (t < 16) {
            int ri = t >> 2, w2 = t & 3;
            u64 kk2 = part[w2][ri];
            u64 o = __shfl_xor(kk2, 1); kk2 = o < kk2 ? o : kk2;
            o = __shfl_xor(kk2, 2);     kk2 = o < kk2 ? o : kk2;
            if (w2 == 0 && ri < cn)
                atomicMin(&slots[k * NPK + base + ri], kk2);
        }
    }
}

// ---------------- write rescored winners + exact scores back ----------------
__global__ void k_fixup(const int* __restrict__ list, const int* __restrict__ cnt,
                        const u64* __restrict__ slots, int* __restrict__ idxw,
                        float* __restrict__ bestv) {
    int g = blockIdx.x * 256 + threadIdx.x;
#pragma unroll
    for (int k = 0; k < K_CB; ++k)
        if (g < cnt[k]) {
            u64 sl = slots[k * NPK + g];
            int gidx = list[k * NPK + g];
            idxw[gidx] = (int)(sl & 0xFFFFFFFFu);
            unsigned int u = (unsigned int)(sl >> 32);
            unsigned int bits = (u & 0x80000000u) ? (u & 0x7FFFFFFFu) : ~u;
            bestv[gidx] = __uint_as_float(bits);
        }
}

// ---------------- gather z_q + argf/hist (emit fused) ----------------
__global__ void k_gather(const float* __restrict__ embed, const int* __restrict__ idx,
                         float* __restrict__ zq, float* __restrict__ argf,
                         int* __restrict__ hist)
{
    const int blk = blockIdx.x;           // k*4096 + b*128 + d
    const int k = blk >> 12;
    const int b = (blk >> 7) & 31;
    const int d = blk & 127;
    const float* erow = embed + ((size_t)k * DIM + d) * NEMB;
    const int* idxr = idx + k * NPK + b * HW;
    float* zr = zq + ((size_t)b * CCH + (size_t)k * DIM + d) * HW;
    const int t = threadIdx.x;
#pragma unroll
    for (int i = 0; i < 4; ++i) {
        int h = i * 256 + t;
        int j = idxr[h];
        zr[h] = erow[j];
        if (d == 0) {
            argf[k * NPK + b * HW + h] = (float)j;
            atomicAdd(&hist[k * NEMB + j], 1);
        }
    }
}

// ---------------- diff partial sums: 64 blocks over the flat 65536 rows ----------------
__global__ void k_dsum(const float* __restrict__ rnorm, const float* __restrict__ bestv,
                       float* __restrict__ dpart)
{
    __shared__ float red[256];
    const int t = threadIdx.x;
    const int base = blockIdx.x * 1024;
    float s = 0.f;
#pragma unroll
    for (int i = 0; i < 4; ++i) {
        int g = base + i * 256 + t;
        s += rnorm[g] + bestv[g];
    }
    red[t] = s;
    __syncthreads();
    for (int off = 128; off > 0; off >>= 1) {
        if (t < off) red[t] += red[t + off];
        __syncthreads();
    }
    if (t == 0) dpart[blockIdx.x] = red[0];
}

// ---------------- finalize diffs + perplexity ----------------
__global__ void k_ppl(const float* __restrict__ dpart, const int* __restrict__ hist,
                      float* __restrict__ diffs, float* __restrict__ ppls)
{
    const int k = blockIdx.x;
    const int t = threadIdx.x;
    __shared__ float red[256];
    red[t] = (t < 32) ? dpart[k * 32 + t] : 0.f;
    __syncthreads();
    for (int off = 128; off > 0; off >>= 1) {
        if (t < off) red[t] += red[t + off];
        __syncthreads();
    }
    if (t == 0) diffs[k] = red[0] / (float)((size_t)NPK * DIM);
    __syncthreads();
    float s2 = 0.f;
    for (int i = t; i < NEMB; i += 256) {
        float p = (float)hist[k * NEMB + i] * (1.0f / (float)NPK);
        s2 += p * logf(p + 1e-10f);
    }
    red[t] = s2;
    __syncthreads();
    for (int off = 128; off > 0; off >>= 1) {
        if (t < off) red[t] += red[t + off];
        __syncthreads();
    }
    if (t == 0) ppls[k] = expf(-red[0]);
}

extern "C" void kernel_launch(void* const* d_in, const int* in_sizes, int n_in,
                              void* d_out, int out_size, void* d_ws, size_t ws_size,
                              hipStream_t stream) {
    const float* x = (const float*)d_in[0];       // [32,256,32,32]
    const float* embed = (const float*)d_in[1];   // [2,128,4096]
    float* out = (float*)d_out;
    float* zq    = out;                 // 8388608
    float* diffs = out + 8388608;       // 2
    float* argf  = out + 8388610;       // 65536 ([K,B,H,W] as float)
    float* ppls  = out + 8454146;       // 2

    char* W = (char*)d_ws;
    ushort* ebf   = (ushort*)W;                    // 2,097,152 : embedT fp16 [2][4096][128]
    float* enorm  = (float*)(W + 2097152);         // 32768 (exact, rescore)
    float* en512  = (float*)(W + 2129920);         // 32768 (+512, coarse)
    int*   idx    = (int*)(W + 2162688);           // 262144
    int*   hist   = (int*)(W + 2424832);           // 32768
    float* rnorm  = (float*)(W + 2457600);         // 262144
    float* bestv  = (float*)(W + 2719744);         // 262144
    int*   list   = (int*)(W + 2981888);           // 262144
    int*   cnt    = (int*)(W + 3244032);           // 64
    u64*   slots  = (u64*)(W + 3244096);           // 524288
    float* dpart  = (float*)(W + 3768384);         // 256 -> ends ~3.77 MB

    k_prep   <<<64,   256, 0, stream>>>(embed, ebf, enorm, en512, hist, cnt, slots);
    k_score  <<<512,  512, 0, stream>>>(x, ebf, en512, idx, bestv, rnorm, list, cnt);
    k_rescore<<<4096, 256, 0, stream>>>(x, embed, enorm, list, cnt, slots);
    k_fixup  <<<128,  256, 0, stream>>>(list, cnt, slots, idx, bestv);
    k_gather <<<8192, 256, 0, stream>>>(embed, idx, zq, argf, hist);
    k_dsum   <<<64,   256, 0, stream>>>(rnorm, bestv, dpart);
    k_ppl    <<<2,    256, 0, stream>>>(dpart, hist, diffs, ppls);
}

// Round 16
// 178.553 us; speedup vs baseline: 1.1364x; 1.0953x over previous
//
#include <hip/hip_runtime.h>
#include <hip/hip_bf16.h>
#include <math.h>

#define K_CB 2
#define DIM 128
#define NEMB 4096
#define HW 1024
#define NPK 32768
#define CCH 256
#define MARGIN 0.13f

typedef __attribute__((ext_vector_type(8))) _Float16 half8;
typedef __attribute__((ext_vector_type(4))) float f32x4;
typedef unsigned long long u64;

// ---------------- embed -> fp16 [k][j][d] + fp32 eT [k][j][d] + ||e||^2 + scratch zero ----------------
__global__ void k_prep(const float* __restrict__ embed, ushort* __restrict__ ebf,
                       float* __restrict__ eT, float* __restrict__ enorm,
                       float* __restrict__ en512, int* __restrict__ hist,
                       int* __restrict__ cnt, u64* __restrict__ slots) {
    __shared__ float tile2[DIM][130];   // fp32 transpose tile (66.5 KB)
    __shared__ float psum[2][128];
    const int t = threadIdx.x;
    const int gb = blockIdx.x * 256 + t;          // 0..16383
#pragma unroll
    for (int i = 0; i < 4; ++i) slots[gb * 4 + i] = ~0ull;   // 65536 slots
    if (gb < K_CB * NEMB) hist[gb] = 0;
    if (gb < K_CB) cnt[gb] = 0;

    const int k = blockIdx.x >> 5;
    const int j0 = (blockIdx.x & 31) * 128;
    const int jj = t & 127, half = t >> 7;
    const float* ek = embed + (size_t)k * DIM * NEMB;
    float s = 0.f;
    for (int i = 0; i < 64; ++i) {
        int d = i * 2 + half;
        float v = ek[(size_t)d * NEMB + j0 + jj];
        s = fmaf(v, v, s);
        tile2[d][jj] = v;
    }
    psum[half][jj] = s;
    __syncthreads();
    if (t < 128) {
        float e = psum[0][t] + psum[1][t];
        enorm[k * NEMB + j0 + t] = e;           // exact, for rescore
        en512[k * NEMB + j0 + t] = e + 512.f;   // shifted, for coarse packed scoring
    }
    ushort* outk = ebf + ((size_t)k * NEMB + j0) * DIM;
    float* outf = eT + ((size_t)k * NEMB + j0) * DIM;
    for (int i = 0; i < 64; ++i) {
        int idx = i * 256 + t;
        int jx = idx >> 7, d = idx & 127;
        float v = tile2[d][jx];
        _Float16 h = (_Float16)v;
        outk[(size_t)jx * DIM + d] = *(ushort*)&h;
        outf[(size_t)jx * DIM + d] = v;
    }
}

// ---------------- coarse fp16 MFMA scoring, packed (score|jloc) epilogue [r9/r15 proven] ----------------
// block (k, 128 rows), 512 threads = 8 waves as (wm 0..3 row-quarters) x (wjj 0..1 j-halves).
// Wave tile 32 rows x 64 j. A in registers; B 2x32KB double-buffered; 4-bit XOR swizzle.
// Scores shifted +512 (positive) -> low 7 mantissa bits carry jloc (perturb <= 0.008).
// REGISTER BUDGET (rounds 10/14 lesson): total arch+acc regs must stay <=128 for
// 2 blocks/CU (unified VGPR/AGPR file). Do NOT add live arrays — occupancy halves.
#define STAGE_B(dst, jt_) do { \
    _Pragma("unroll") \
    for (int it = 0; it < 4; ++it) { \
        int seg_ = it * 512 + t; \
        int row_ = seg_ >> 4; \
        int slot_ = seg_ & 15; \
        int src_ = row_ * 256 + ((slot_ * 16) ^ ((row_ & 15) << 4)); \
        const char* g_ = (const char*)ebk + (size_t)(jt_) * 32768 + src_; \
        char* l_ = (char*)(dst) + (it * 512 + (t & ~63)) * 16; \
        __builtin_amdgcn_global_load_lds( \
            (const __attribute__((address_space(1))) unsigned int*)g_, \
            (__attribute__((address_space(3))) unsigned int*)l_, 16, 0, 0); \
    } \
} while (0)

__launch_bounds__(512, 4)
__global__ void k_score(const float* __restrict__ x, const ushort* __restrict__ ebf,
                        const float* __restrict__ en512, int* __restrict__ idxw,
                        float* __restrict__ bestv, float* __restrict__ rnorm,
                        int* __restrict__ list, int* __restrict__ cnt)
{
    __shared__ __align__(16) char smem[65536];
    __shared__ float rn[4][128];
    char* Bs0 = smem;
    char* Bs1 = smem + 32768;

    const int blk = blockIdx.x;
    const int k = blk >> 8;
    const int n0 = (blk & 255) * 128;
    const int b = n0 >> 10;
    const int hw0 = n0 & (HW - 1);
    const int t = threadIdx.x;          // 0..511
    const int lane = t & 63;
    const int w = t >> 6;               // 0..7
    const int wm = w >> 1;              // row quarter
    const int wjj = w & 1;              // j half
    const int l15 = lane & 15, l4 = lane >> 4;

    const ushort* ebk = ebf + (size_t)k * NEMB * DIM;
    const float* enk = en512 + k * NEMB;
    const float* xk = x + ((size_t)(b * CCH + k * DIM)) * HW + hw0;

    // ---- prologue: stage A [n=128][d=128] fp16 swizzled (uses both B buffers' space) ----
    {
        const int h = t & 127, q = t >> 7;   // q 0..3 (d-quarter)
        float s = 0.f;
        for (int i = 0; i < 16; ++i) {
            int d2 = q * 32 + i * 2;
            float v0 = xk[(size_t)d2 * HW + h];
            float v1 = xk[(size_t)(d2 + 1) * HW + h];
            s = fmaf(v0, v0, fmaf(v1, v1, s));
            _Float16 h0 = (_Float16)v0, h1 = (_Float16)v1;
            unsigned int u = ((unsigned int)*(ushort*)&h0) | (((unsigned int)*(ushort*)&h1) << 16);
            int byte = h * 256 + ((d2 * 2) ^ ((h & 15) << 4));
            *(unsigned int*)(smem + byte) = u;
        }
        rn[q][h] = s;
    }
    __syncthreads();
    if (t < 128) rnorm[k * NPK + n0 + t] = rn[0][t] + rn[1][t] + rn[2][t] + rn[3][t];

    // ---- A-frags to registers: 2 mf x 4 kk (this wave's 32 rows) ----
    half8 areg[2][4];
#pragma unroll
    for (int mf = 0; mf < 2; ++mf)
#pragma unroll
        for (int kk = 0; kk < 4; ++kk) {
            int row = wm * 32 + mf * 16 + l15;
            int byte = row * 256 + ((kk * 64 + l4 * 16) ^ ((row & 15) << 4));
            areg[mf][kk] = *(const half8*)(smem + byte);
        }
    __syncthreads();   // A reads done before B staging overwrites

    STAGE_B(Bs0, 0);
    __syncthreads();   // Bs0 ready

    const f32x4 z4 = {0.f, 0.f, 0.f, 0.f};
    const int jlbase = wjj * 64 + l15;   // low-7 jloc base for this lane

    float best[8], second[8];
    int bchunk[8];
#pragma unroll
    for (int i = 0; i < 8; ++i) { best[i] = 3.4e38f; second[i] = 3.4e38f; bchunk[i] = 0; }

    for (int jt = 0; jt < 32; ++jt) {
        const char* Bc = (jt & 1) ? Bs1 : Bs0;
        char* Bn = (jt & 1) ? Bs0 : Bs1;
        if (jt < 31) STAGE_B(Bn, jt + 1);

        f32x4 acc[2][4];
#pragma unroll
        for (int kk = 0; kk < 4; ++kk) {
            half8 bb[4];
#pragma unroll
            for (int jf = 0; jf < 4; ++jf) {
                int row = wjj * 64 + jf * 16 + l15;
                int byte = row * 256 + ((kk * 64 + l4 * 16) ^ ((row & 15) << 4));
                bb[jf] = *(const half8*)(Bc + byte);
            }
#pragma unroll
            for (int mf = 0; mf < 2; ++mf)
#pragma unroll
                for (int jf = 0; jf < 4; ++jf)
                    acc[mf][jf] = __builtin_amdgcn_mfma_f32_16x16x32_f16(
                        areg[mf][kk], bb[jf], (kk == 0) ? z4 : acc[mf][jf], 0, 0, 0);
        }

        // ---- epilogue: packed (score|jloc), per-row min-tree + (best, second, chunk) ----
        float en[4];
#pragma unroll
        for (int jf = 0; jf < 4; ++jf) en[jf] = enk[jt * 128 + wjj * 64 + jf * 16 + l15];
#pragma unroll
        for (int mf = 0; mf < 2; ++mf)
#pragma unroll
            for (int r = 0; r < 4; ++r) {
                int ti = mf * 4 + r;
                float p0 = __uint_as_float((__float_as_uint(fmaf(-2.f, acc[mf][0][r], en[0])) & 0xFFFFFF80u) | (jlbase));
                float p1 = __uint_as_float((__float_as_uint(fmaf(-2.f, acc[mf][1][r], en[1])) & 0xFFFFFF80u) | (jlbase + 16));
                float p2 = __uint_as_float((__float_as_uint(fmaf(-2.f, acc[mf][2][r], en[2])) & 0xFFFFFF80u) | (jlbase + 32));
                float p3 = __uint_as_float((__float_as_uint(fmaf(-2.f, acc[mf][3][r], en[3])) & 0xFFFFFF80u) | (jlbase + 48));
                float m = fminf(fminf(p0, p1), fminf(p2, p3));
                second[ti] = fminf(second[ti], fmaxf(m, best[ti]));
                bool lt = m < best[ti];
                bchunk[ti] = lt ? jt : bchunk[ti];
                best[ti] = fminf(best[ti], m);
            }
        __syncthreads();   // next tile's staged buffer ready
    }

    // ---- merge across the 16 j-lanes sharing each row (packed values distinct per lane) ----
#pragma unroll
    for (int off = 1; off < 16; off <<= 1) {
#pragma unroll
        for (int ti = 0; ti < 8; ++ti) {
            float ob = __shfl_xor(best[ti], off);
            float os = __shfl_xor(second[ti], off);
            int oc = __shfl_xor(bchunk[ti], off);
            float ns = fminf(fmaxf(best[ti], ob), fminf(second[ti], os));
            bool take = ob < best[ti];
            bchunk[ti] = take ? oc : bchunk[ti];
            best[ti] = fminf(best[ti], ob);
            second[ti] = ns;
        }
    }

    // ---- merge the two wjj waves per row via LDS ----
    __syncthreads();
    float* tb = (float*)smem;          // [128][2]
    float* ts = tb + 256;              // [128][2]
    int*   tc = (int*)(ts + 256);      // [128][2]
    if (l15 == 0) {
#pragma unroll
        for (int ti = 0; ti < 8; ++ti) {
            int mf = ti >> 2, r = ti & 3;
            int row = wm * 32 + mf * 16 + l4 * 4 + r;
            tb[row * 2 + wjj] = best[ti];
            ts[row * 2 + wjj] = second[ti];
            tc[row * 2 + wjj] = bchunk[ti];
        }
    }
    __syncthreads();
    if (t < 128) {
        float b0 = tb[t * 2], b1 = tb[t * 2 + 1];
        float s0 = ts[t * 2], s1 = ts[t * 2 + 1];
        int   c0 = tc[t * 2], c1 = tc[t * 2 + 1];
        bool take1 = b1 < b0;                    // packed values distinct (wjj bit)
        float nb = fminf(b0, b1);
        float ns = fminf(fmaxf(b0, b1), fminf(s0, s1));
        int   nc = take1 ? c1 : c0;
        unsigned int nbits = __float_as_uint(nb);
        int nj = nc * 128 + (int)(nbits & 127u);
        int gidx = k * NPK + n0 + t;
        idxw[gidx] = nj;
        bestv[gidx] = __uint_as_float(nbits & 0xFFFFFF80u) - 512.f;
        if (ns - nb < MARGIN) {
            int p = atomicAdd(&cnt[k], 1);
            list[k * NPK + p] = gidx;
        }
    }
}

// ---------------- exact fp32 rescore: (8-row chunk) x (256-j slab) items ----------------
// 8 rows/chunk halves codebook L2 re-read traffic vs 4-row (~2.25 GB -> ~1.1 GB);
// dot[8]+key[8] = +12 regs over the 4-row shape (r12's 16-row blew registers).
__launch_bounds__(256, 4)
__global__ void k_rescore(const float* __restrict__ x, const float* __restrict__ embed,
                          const float* __restrict__ enorm, const int* __restrict__ list,
                          const int* __restrict__ cnt, u64* __restrict__ slots)
{
    __shared__ float xr[8][128];
    __shared__ u64 part[4][8];
    const int t = threadIdx.x;
    const int lane = t & 63, wv = t >> 6;
    const int c0 = cnt[0], c1 = cnt[1];
    const int items0 = ((c0 + 7) >> 3) * 16;
    const int items1 = ((c1 + 7) >> 3) * 16;
    const int total = items0 + items1;

    for (int item = blockIdx.x; item < total; item += gridDim.x) {
        int k, c, sl, ck;
        if (item < items0) { k = 0; c = item >> 4; sl = item & 15; ck = c0; }
        else { int it2 = item - items0; k = 1; c = it2 >> 4; sl = it2 & 15; ck = c1; }
        const int base = c * 8;
        const int cn = min(8, ck - base);
        __syncthreads();   // xr/part reuse safety
        for (int ii = t; ii < cn * 128; ii += 256) {
            int ri = ii >> 7, d = ii & 127;
            int gidx = list[k * NPK + base + ri];
            int n = gidx & (NPK - 1);
            int bb = n >> 10, hw = n & 1023;
            xr[ri][d] = x[((size_t)(bb * CCH + k * DIM + d)) * HW + hw];
        }
        __syncthreads();

        const int j = sl * 256 + t;
        float dot[8];
#pragma unroll
        for (int ri = 0; ri < 8; ++ri) dot[ri] = 0.f;
        const float* ek = embed + (size_t)k * DIM * NEMB + j;
        for (int d = 0; d < DIM; ++d) {
            float ev = ek[(size_t)d * NEMB];
#pragma unroll
            for (int ri = 0; ri < 8; ++ri) dot[ri] = fmaf(xr[ri][d], ev, dot[ri]);
        }
        const float en = enorm[k * NEMB + j];
        u64 key[8];
#pragma unroll
        for (int ri = 0; ri < 8; ++ri) {
            float sc = fmaf(-2.f, dot[ri], en);
            unsigned int bits = __float_as_uint(sc);
            unsigned int u = (sc >= 0.f) ? (bits | 0x80000000u) : ~bits;
            key[ri] = ((u64)u << 32) | (unsigned int)j;
        }
#pragma unroll
        for (int off = 32; off; off >>= 1) {
#pragma unroll
            for (int ri = 0; ri < 8; ++ri) {
                u64 o = __shfl_xor(key[ri], off);
                key[ri] = o < key[ri] ? o : key[ri];
            }
        }
        if (lane == 0) {
#pragma unroll
            for (int ri = 0; ri < 8; ++ri) part[wv][ri] = key[ri];
        }
        __syncthreads();
        if (t < 32) {
            int ri = t >> 2, w2 = t & 3;
            u64 kk2 = part[w2][ri];
            u64 o = __shfl_xor(kk2, 1); kk2 = o < kk2 ? o : kk2;
            o = __shfl_xor(kk2, 2);     kk2 = o < kk2 ? o : kk2;
            if (w2 == 0 && ri < cn)
                atomicMin(&slots[k * NPK + base + ri], kk2);
        }
    }
}

// ---------------- write rescored winners + exact scores back ----------------
__global__ void k_fixup(const int* __restrict__ list, const int* __restrict__ cnt,
                        const u64* __restrict__ slots, int* __restrict__ idxw,
                        float* __restrict__ bestv) {
    int g = blockIdx.x * 256 + threadIdx.x;
#pragma unroll
    for (int k = 0; k < K_CB; ++k)
        if (g < cnt[k]) {
            u64 sl = slots[k * NPK + g];
            int gidx = list[k * NPK + g];
            idxw[gidx] = (int)(sl & 0xFFFFFFFFu);
            unsigned int u = (unsigned int)(sl >> 32);
            unsigned int bits = (u & 0x80000000u) ? (u & 0x7FFFFFFFu) : ~u;
            bestv[gidx] = __uint_as_float(bits);
        }
}

// ---------------- gather z_q via LDS row-stage + transpose (coalesced both sides) ----------------
// block = (k, b, 64-hw tile): stage the 64 selected eT rows (512 B coalesced reads),
// write zq coalesced; [129]-padded LDS makes the transpose read conflict-free.
__global__ void k_gather(const float* __restrict__ eT, const int* __restrict__ idx,
                         float* __restrict__ zq, float* __restrict__ argf,
                         int* __restrict__ hist)
{
    __shared__ int js[64];
    __shared__ float el[64][129];
    const int blk = blockIdx.x;           // k*512 + b*16 + hwt
    const int k = blk >> 9;
    const int b = (blk >> 4) & 31;
    const int hw0 = (blk & 15) * 64;
    const int t = threadIdx.x;
    const int* idxr = idx + k * NPK + b * HW + hw0;
    if (t < 64) {
        int j = idxr[t];
        js[t] = j;
        argf[k * NPK + b * HW + hw0 + t] = (float)j;
        atomicAdd(&hist[k * NEMB + j], 1);
    }
    __syncthreads();
    const float* ek = eT + (size_t)k * NEMB * DIM;
#pragma unroll
    for (int i = 0; i < 32; ++i) {
        int o = i * 256 + t;
        int r = o >> 7, d = o & 127;
        el[r][d] = ek[(size_t)js[r] * DIM + d];
    }
    __syncthreads();
    float* zr = zq + ((size_t)(b * CCH + k * DIM)) * HW + hw0;
#pragma unroll
    for (int i = 0; i < 32; ++i) {
        int o = i * 256 + t;
        int d = o >> 6, h = o & 63;
        zr[(size_t)d * HW + h] = el[h][d];
    }
}

// ---------------- diff partial sums: 64 blocks over the flat 65536 rows ----------------
__global__ void k_dsum(const float* __restrict__ rnorm, const float* __restrict__ bestv,
                       float* __restrict__ dpart)
{
    __shared__ float red[256];
    const int t = threadIdx.x;
    const int base = blockIdx.x * 1024;
    float s = 0.f;
#pragma unroll
    for (int i = 0; i < 4; ++i) {
        int g = base + i * 256 + t;
        s += rnorm[g] + bestv[g];
    }
    red[t] = s;
    __syncthreads();
    for (int off = 128; off > 0; off >>= 1) {
        if (t < off) red[t] += red[t + off];
        __syncthreads();
    }
    if (t == 0) dpart[blockIdx.x] = red[0];
}

// ---------------- finalize diffs + perplexity ----------------
__global__ void k_ppl(const float* __restrict__ dpart, const int* __restrict__ hist,
                      float* __restrict__ diffs, float* __restrict__ ppls)
{
    const int k = blockIdx.x;
    const int t = threadIdx.x;
    __shared__ float red[256];
    red[t] = (t < 32) ? dpart[k * 32 + t] : 0.f;
    __syncthreads();
    for (int off = 128; off > 0; off >>= 1) {
        if (t < off) red[t] += red[t + off];
        __syncthreads();
    }
    if (t == 0) diffs[k] = red[0] / (float)((size_t)NPK * DIM);
    __syncthreads();
    float s2 = 0.f;
    for (int i = t; i < NEMB; i += 256) {
        float p = (float)hist[k * NEMB + i] * (1.0f / (float)NPK);
        s2 += p * logf(p + 1e-10f);
    }
    red[t] = s2;
    __syncthreads();
    for (int off = 128; off > 0; off >>= 1) {
        if (t < off) red[t] += red[t + off];
        __syncthreads();
    }
    if (t == 0) ppls[k] = expf(-red[0]);
}

extern "C" void kernel_launch(void* const* d_in, const int* in_sizes, int n_in,
                              void* d_out, int out_size, void* d_ws, size_t ws_size,
                              hipStream_t stream) {
    const float* x = (const float*)d_in[0];       // [32,256,32,32]
    const float* embed = (const float*)d_in[1];   // [2,128,4096]
    float* out = (float*)d_out;
    float* zq    = out;                 // 8388608
    float* diffs = out + 8388608;       // 2
    float* argf  = out + 8388610;       // 65536 ([K,B,H,W] as float)
    float* ppls  = out + 8454146;       // 2

    char* W = (char*)d_ws;
    ushort* ebf   = (ushort*)W;                    // 2,097,152 : embedT fp16 [2][4096][128]
    float* enorm  = (float*)(W + 2097152);         // 32768 (exact, rescore)
    float* en512  = (float*)(W + 2129920);         // 32768 (+512, coarse)
    int*   idx    = (int*)(W + 2162688);           // 262144
    int*   hist   = (int*)(W + 2424832);           // 32768
    float* rnorm  = (float*)(W + 2457600);         // 262144
    float* bestv  = (float*)(W + 2719744);         // 262144
    int*   list   = (int*)(W + 2981888);           // 262144
    int*   cnt    = (int*)(W + 3244032);           // 64
    u64*   slots  = (u64*)(W + 3244096);           // 524288
    float* dpart  = (float*)(W + 3768384);         // 256
    float* eT     = (float*)(W + 3768640);         // 4,194,304 : embedT fp32 -> ends ~7.96 MB

    k_prep   <<<64,   256, 0, stream>>>(embed, ebf, eT, enorm, en512, hist, cnt, slots);
    k_score  <<<512,  512, 0, stream>>>(x, ebf, en512, idx, bestv, rnorm, list, cnt);
    k_rescore<<<4096, 256, 0, stream>>>(x, embed, enorm, list, cnt, slots);
    k_fixup  <<<128,  256, 0, stream>>>(list, cnt, slots, idx, bestv);
    k_gather <<<1024, 256, 0, stream>>>(eT, idx, zq, argf, hist);
    k_dsum   <<<64,   256, 0, stream>>>(rnorm, bestv, dpart);
    k_ppl    <<<2,    256, 0, stream>>>(dpart, hist, diffs, ppls);
}